// Round 9
// baseline (812.495 us; speedup 1.0000x reference)
//
#include <hip/hip_runtime.h>
#include <hip/hip_bf16.h>

// BiAttention: B=16, L=M=2048, D=1024.
//  conv -> tr -> gemm1(S=QK^T+dots,mask) -> softmax_rows -> w2a(+o2 zero) -> o2 -> gemm2(fused epilogue)
// R9: both GEMMs = 256^2 8-phase template (T3+T4+T5): BK=64 dbuf (128KB LDS),
// 8 waves 2Mx4N, per K-tile 4 quadrant-phases {ds_read; stage; s_barrier;
// lgkmcnt(0); setprio; 16 MFMA; setprio; s_barrier}; stages front-loaded
// (phases 1-2) into opposite buffer; single counted boundary vmcnt(0) at
// phase 4 (issue-to-wait = 3 phases of cover). RAW: per-wave vmcnt + barrier.
// WAR: opposite-parity buffer. NO __syncthreads in K-loop (it drains vmcnt).
// Epilogues: R8's LDS-staged vectorized writes (reuse smem after K-loop).

#define BDIM 16
#define LDIM 2048
#define MDIM 2048
#define DDIM 1024
#define NEGF (-60000.0f)

typedef float    f32x4v __attribute__((ext_vector_type(4)));
typedef _Float16 half8  __attribute__((ext_vector_type(8)));
typedef _Float16 half4  __attribute__((ext_vector_type(4)));

#define GL16(gp, lp)                                                        \
  __builtin_amdgcn_global_load_lds(                                         \
      (const __attribute__((address_space(1))) unsigned int*)(gp),          \
      (__attribute__((address_space(3))) unsigned int*)(lp), 16, 0, 0)

#define LGKM0 asm volatile("s_waitcnt lgkmcnt(0)" ::: "memory")
#define VMC0  asm volatile("s_waitcnt vmcnt(0)" ::: "memory")
#define BAR   __builtin_amdgcn_s_barrier()

__device__ __forceinline__ float4 m4(const float4 a, const float4 b) {
  return (float4){a.x * b.x, a.y * b.y, a.z * b.z, a.w * b.w};
}
__device__ __forceinline__ void nts4(const float4 v, float* p) {
  f32x4v w = {v.x, v.y, v.z, v.w};
  __builtin_nontemporal_store(w, (f32x4v*)p);
}

// ---------------- conversion + row dots ----------------
__global__ __launch_bounds__(256) void conv_kernel(
    const float* __restrict__ input, const float* __restrict__ memory,
    const float* __restrict__ w_in, const float* __restrict__ w_mem,
    const float* __restrict__ scale,
    _Float16* __restrict__ Qh, _Float16* __restrict__ Kh,
    float* __restrict__ idot, float* __restrict__ mdot) {
  const int t = threadIdx.x, lane = t & 63, wid = t >> 6;
  const size_t row = (size_t)blockIdx.x * 4 + wid;
  const float* ir  = input  + row * DDIM;
  const float* mrp = memory + row * DDIM;
  float di = 0.f, dm = 0.f;
#pragma unroll
  for (int c = 0; c < 4; ++c) {
    const int off = c * 256 + lane * 4;
    float4 sc4 = *(const float4*)&scale[off];
    float4 wi4 = *(const float4*)&w_in[off];
    float4 wm4 = *(const float4*)&w_mem[off];
    float4 v = *(const float4*)&ir[off];
    di += v.x * wi4.x + v.y * wi4.y + v.z * wi4.z + v.w * wi4.w;
    half4 q = { (_Float16)(v.x * sc4.x), (_Float16)(v.y * sc4.y),
                (_Float16)(v.z * sc4.z), (_Float16)(v.w * sc4.w) };
    *(half4*)&Qh[row * DDIM + off] = q;
    float4 u = *(const float4*)&mrp[off];
    dm += u.x * wm4.x + u.y * wm4.y + u.z * wm4.z + u.w * wm4.w;
    half4 k = { (_Float16)u.x, (_Float16)u.y, (_Float16)u.z, (_Float16)u.w };
    *(half4*)&Kh[row * DDIM + off] = k;
  }
#pragma unroll
  for (int o = 1; o < 64; o <<= 1) {
    di += __shfl_xor(di, o, 64);
    dm += __shfl_xor(dm, o, 64);
  }
  if (lane == 0) { idot[row] = di; mdot[row] = dm; }
}

// ---------------- transpose memory (f16) -> Vt[b][d][m] ----------------
__global__ __launch_bounds__(256) void tr_kernel(const _Float16* __restrict__ Kh,
                                                 _Float16* __restrict__ Vt) {
  const int b = blockIdx.z;
  const int d0 = blockIdx.x * 64, m0 = blockIdx.y * 64;
  __shared__ _Float16 sT[64][80];
  const int t = threadIdx.x;
  {
    const int mr = t >> 2, ch = (t & 3) * 16;
    const _Float16* src = Kh + ((size_t)b * MDIM + m0 + mr) * DDIM + d0 + ch;
    *(half8*)&sT[mr][ch]     = *(const half8*)&src[0];
    *(half8*)&sT[mr][ch + 8] = *(const half8*)&src[8];
  }
  __syncthreads();
  {
    const int dr = t >> 2, mc = (t & 3) * 16;
    union { _Float16 h[16]; half8 v[2]; } tmp;
#pragma unroll
    for (int j = 0; j < 16; ++j) tmp.h[j] = sT[mc + j][dr];
    _Float16* dst = Vt + ((size_t)b * DDIM + d0 + dr) * MDIM + m0 + mc;
    *(half8*)&dst[0] = tmp.v[0];
    *(half8*)&dst[8] = tmp.v[1];
  }
}

// ============ 256^2 8-phase GEMM core ============
// stage rows row0..row0+127 of one matrix (2 GL16/thread); linear LDS dest,
// inverse-permuted source chunk (LDS chunk q of row r holds src chunk q^(r&7)).
__device__ __forceinline__ void stage_half128(const _Float16* __restrict__ src,
                                              _Float16* dst, int stride, int k0,
                                              int row0, int wid, int lane) {
#pragma unroll
  for (int j = 0; j < 2; ++j) {
    const int r0 = row0 + j * 64 + wid * 8;      // wave-uniform 8-row chunk
    const int r  = r0 + (lane >> 3);
    const int sc = ((lane & 7) ^ (r & 7)) * 8;
    GL16(src + (size_t)r * stride + k0 + sc, dst + r0 * 64);
  }
}

// swizzled fragment read: source chunk kc (0..7) of row (conflict-free, R5-verified)
__device__ __forceinline__ half8 rdfrag(const _Float16* buf, int row, int kc) {
  return *(const half8*)&buf[row * 64 + ((kc ^ (row & 7)) << 3)];
}

__device__ __forceinline__ void gemm_loop(const _Float16* __restrict__ Ab,
                                          const _Float16* __restrict__ Bb,
                                          int stride, int NT, _Float16* s,
                                          f32x4v acc[8][4], int wid, int lane,
                                          int wrow, int wcol) {
  _Float16* sA[2] = {s, s + 16384};
  _Float16* sB[2] = {s + 32768, s + 49152};
  const int kq = lane >> 4, l15 = lane & 15;
  // prologue: stage tile 0 fully into buf0
  stage_half128(Ab, sA[0], stride, 0, 0,   wid, lane);
  stage_half128(Bb, sB[0], stride, 0, 0,   wid, lane);
  stage_half128(Ab, sA[0], stride, 0, 128, wid, lane);
  stage_half128(Bb, sB[0], stride, 0, 128, wid, lane);
  VMC0; BAR;

  for (int tt = 0; tt < NT; ++tt) {
    const _Float16* cA = sA[tt & 1];
    const _Float16* cB = sB[tt & 1];
    _Float16* nA = sA[(tt + 1) & 1];
    _Float16* nB = sB[(tt + 1) & 1];
    const bool st = (tt + 1 < NT);
    const int nk0 = (tt + 1) * 64;
    half8 a0[4], a1[4], b0[4], b1[4];
    // ---- phase 1: quadrant (m-half 0, kk0); read bF(kk0)+aF; stage A/B top(t+1)
#pragma unroll
    for (int n = 0; n < 4; ++n) b0[n] = rdfrag(cB, wcol * 64 + n * 16 + l15, kq);
#pragma unroll
    for (int i = 0; i < 4; ++i) a0[i] = rdfrag(cA, wrow * 128 + i * 16 + l15, kq);
    if (st) {
      stage_half128(Ab, nA, stride, nk0, 0, wid, lane);
      stage_half128(Bb, nB, stride, nk0, 0, wid, lane);
    }
    BAR; LGKM0;
    __builtin_amdgcn_s_setprio(1);
#pragma unroll
    for (int i = 0; i < 4; ++i)
#pragma unroll
      for (int n = 0; n < 4; ++n)
        acc[i][n] = __builtin_amdgcn_mfma_f32_16x16x32_f16(a0[i], b0[n], acc[i][n], 0, 0, 0);
    __builtin_amdgcn_s_setprio(0);
    BAR;
    // ---- phase 2: (m-half 1, kk0); stage A/B bottom(t+1)
#pragma unroll
    for (int i = 0; i < 4; ++i) a1[i] = rdfrag(cA, wrow * 128 + (4 + i) * 16 + l15, kq);
    if (st) {
      stage_half128(Ab, nA, stride, nk0, 128, wid, lane);
      stage_half128(Bb, nB, stride, nk0, 128, wid, lane);
    }
    BAR; LGKM0;
    __builtin_amdgcn_s_setprio(1);
#pragma unroll
    for (int i = 0; i < 4; ++i)
#pragma unroll
      for (int n = 0; n < 4; ++n)
        acc[4 + i][n] = __builtin_amdgcn_mfma_f32_16x16x32_f16(a1[i], b0[n], acc[4 + i][n], 0, 0, 0);
    __builtin_amdgcn_s_setprio(0);
    BAR;
    // ---- phase 3: (m-half 0, kk1); read bF(kk1)+aF
#pragma unroll
    for (int n = 0; n < 4; ++n) b1[n] = rdfrag(cB, wcol * 64 + n * 16 + l15, 4 + kq);
#pragma unroll
    for (int i = 0; i < 4; ++i) a0[i] = rdfrag(cA, wrow * 128 + i * 16 + l15, 4 + kq);
    BAR; LGKM0;
    __builtin_amdgcn_s_setprio(1);
#pragma unroll
    for (int i = 0; i < 4; ++i)
#pragma unroll
      for (int n = 0; n < 4; ++n)
        acc[i][n] = __builtin_amdgcn_mfma_f32_16x16x32_f16(a0[i], b1[n], acc[i][n], 0, 0, 0);
    __builtin_amdgcn_s_setprio(0);
    BAR;
    // ---- phase 4: (m-half 1, kk1); boundary counted wait
#pragma unroll
    for (int i = 0; i < 4; ++i) a1[i] = rdfrag(cA, wrow * 128 + (4 + i) * 16 + l15, 4 + kq);
    BAR; LGKM0;
    __builtin_amdgcn_s_setprio(1);
#pragma unroll
    for (int i = 0; i < 4; ++i)
#pragma unroll
      for (int n = 0; n < 4; ++n)
        acc[4 + i][n] = __builtin_amdgcn_mfma_f32_16x16x32_f16(a1[i], b1[n], acc[4 + i][n], 0, 0, 0);
    __builtin_amdgcn_s_setprio(0);
    if (st) VMC0;      // t+1's 8 loads issued ~3 phases ago -> mostly landed
    BAR;
  }
}

// ---------------- GEMM1: S = Q @ K^T + dots, masked (256^2, 8-phase) ----------------
__global__ __launch_bounds__(512, 2) void gemm1_kernel(
    const _Float16* __restrict__ Qh, const _Float16* __restrict__ Kh,
    const float* __restrict__ idot, const float* __restrict__ mdot,
    const int* __restrict__ mask, _Float16* __restrict__ Sp) {
  const int id = blockIdx.x;                 // nwg = 1024
  const int wg = (id & 7) * 128 + (id >> 3);
  const int b = wg >> 6, rem = wg & 63, by = rem >> 3, bx = rem & 7;
  const int t = threadIdx.x, lane = t & 63, wid = t >> 6;
  const int wrow = wid >> 2, wcol = wid & 3, l15 = lane & 15;
  __shared__ _Float16 smem[65536];           // 128 KB: A dbuf + B dbuf
  __shared__ float s_dl[256], s_dm[256];
  __shared__ int   s_ml[256], s_mm[256];
  if (t < 256) {
    s_dl[t] = idot[b * LDIM + by * 256 + t];
    s_ml[t] = mask[b * LDIM + by * 256 + t];
    s_dm[t] = mdot[b * MDIM + bx * 256 + t];
    s_mm[t] = mask[b * MDIM + bx * 256 + t];
  }
  const _Float16* Ab = Qh + ((size_t)b * LDIM + by * 256) * DDIM;
  const _Float16* Bb = Kh + ((size_t)b * MDIM + bx * 256) * DDIM;
  f32x4v acc[8][4];
#pragma unroll
  for (int i = 0; i < 8; ++i)
#pragma unroll
    for (int j = 0; j < 4; ++j) acc[i][j] = (f32x4v){0.f, 0.f, 0.f, 0.f};

  gemm_loop(Ab, Bb, DDIM, DDIM / 64, smem, acc, wid, lane, wrow, wcol);

  // epilogue: 4 panels of 64 rows staged f16 in LDS, half8 row writes
  _Float16* sS = smem;                       // [64][264]
  __syncthreads();
#pragma unroll
  for (int p = 0; p < 4; ++p) {
    if (wrow == (p >> 1)) {
#pragma unroll
      for (int i2 = 0; i2 < 4; ++i2) {
        const int mi = (p & 1) * 4 + i2;
#pragma unroll
        for (int n = 0; n < 4; ++n)
#pragma unroll
          for (int r = 0; r < 4; ++r) {
            const int lr = i2 * 16 + (lane >> 4) * 4 + r;
            const int col = wcol * 64 + n * 16 + l15;
            const int row256 = p * 64 + lr;
            float sv = acc[mi][n][r] + s_dl[row256] + s_dm[col];
            if ((s_ml[row256] | s_mm[col]) != 0) sv = NEGF;
            sS[lr * 264 + col] = (_Float16)sv;
          }
      }
    }
    __syncthreads();
    const int rr = t >> 3, ch = (t & 7) * 32;
    const size_t gro = ((size_t)b * LDIM + by * 256 + p * 64 + rr) * MDIM + bx * 256 + ch;
#pragma unroll
    for (int j = 0; j < 4; ++j)
      *(half8*)&Sp[gro + j * 8] = *(const half8*)&sS[rr * 264 + ch + j * 8];
    __syncthreads();
  }
}

// ---------------- per-row softmax (in place) + rowmax ----------------
__global__ __launch_bounds__(256) void softmax_rows(_Float16* __restrict__ Sp,
                                                    float* __restrict__ rmax) {
  const int t = threadIdx.x, lane = t & 63, wid = t >> 6;
  const size_t row = (size_t)blockIdx.x * 4 + wid;
  _Float16* rp = Sp + row * (size_t)MDIM;
  float s[32];
#pragma unroll
  for (int c = 0; c < 4; ++c) {
    half8 v = *(const half8*)&rp[c * 512 + lane * 8];
#pragma unroll
    for (int j = 0; j < 8; ++j) s[c * 8 + j] = (float)v[j];
  }
  float m = -3.0e38f;
#pragma unroll
  for (int i = 0; i < 32; ++i) m = fmaxf(m, s[i]);
#pragma unroll
  for (int o = 1; o < 64; o <<= 1) m = fmaxf(m, __shfl_xor(m, o, 64));
  float sum = 0.f;
#pragma unroll
  for (int i = 0; i < 32; ++i) { s[i] = __expf(s[i] - m); sum += s[i]; }
#pragma unroll
  for (int o = 1; o < 64; o <<= 1) sum += __shfl_xor(sum, o, 64);
  const float inv = 1.f / sum;
#pragma unroll
  for (int c = 0; c < 4; ++c) {
    half8 v;
#pragma unroll
    for (int j = 0; j < 8; ++j) v[j] = (_Float16)(s[c * 8 + j] * inv);
    *(half8*)&rp[c * 512 + lane * 8] = v;
  }
  if (lane == 0) rmax[row] = m;
}

// ---------------- w2 = softmax_l(rowmax) per batch (+ zero o2) ----------------
__global__ __launch_bounds__(256) void w2a_kernel(const float* __restrict__ rmax,
                                                  float* __restrict__ w2,
                                                  float* __restrict__ o2) {
  const int b = blockIdx.x, t = threadIdx.x;
  ((float4*)(o2 + (size_t)b * DDIM))[t] = (float4){0.f, 0.f, 0.f, 0.f};
  __shared__ float red[256];
  const float* rm = rmax + (size_t)b * LDIM;
  float vals[8]; float lm = -3.0e38f;
#pragma unroll
  for (int j = 0; j < 8; ++j) { vals[j] = rm[t + j * 256]; lm = fmaxf(lm, vals[j]); }
  red[t] = lm; __syncthreads();
  for (int s = 128; s > 0; s >>= 1) {
    if (t < s) red[t] = fmaxf(red[t], red[t + s]);
    __syncthreads();
  }
  const float M = red[0]; __syncthreads();
  float ls = 0.f;
#pragma unroll
  for (int j = 0; j < 8; ++j) ls += __expf(vals[j] - M);
  red[t] = ls; __syncthreads();
  for (int s = 128; s > 0; s >>= 1) {
    if (t < s) red[t] += red[t + s];
    __syncthreads();
  }
  const float inv = 1.f / red[0];
#pragma unroll
  for (int j = 0; j < 8; ++j) w2[(size_t)b * LDIM + t + j * 256] = __expf(vals[j] - M) * inv;
}

// ---------------- o2 ----------------
__global__ __launch_bounds__(256) void o2_kernel(const float* __restrict__ input,
                                                 const float* __restrict__ w2,
                                                 float* __restrict__ o2) {
  const int b = blockIdx.y, ch = blockIdx.x, t = threadIdx.x;
  __shared__ float sw[128];
  if (t < 128) sw[t] = w2[(size_t)b * LDIM + ch * 128 + t];
  __syncthreads();
  const float* ib = input + ((size_t)b * LDIM + ch * 128) * DDIM;
  float4 acc = {0.f, 0.f, 0.f, 0.f};
  for (int l = 0; l < 128; ++l) {
    const float w = sw[l];
    float4 v = *(const float4*)&ib[(size_t)l * DDIM + t * 4];
    acc.x += w * v.x; acc.y += w * v.y; acc.z += w * v.z; acc.w += w * v.w;
  }
  atomicAdd(&o2[b * DDIM + t * 4 + 0], acc.x);
  atomicAdd(&o2[b * DDIM + t * 4 + 1], acc.y);
  atomicAdd(&o2[b * DDIM + t * 4 + 2], acc.z);
  atomicAdd(&o2[b * DDIM + t * 4 + 3], acc.w);
}

// ---------------- GEMM2: o1 = P @ V (256^2, 8-phase), fused epilogue ----------------
__global__ __launch_bounds__(512, 2) void gemm2_kernel(
    const _Float16* __restrict__ Pm, const _Float16* __restrict__ Vt,
    const float* __restrict__ input, const float* __restrict__ o2,
    float* __restrict__ out) {
  const int id = blockIdx.x;                 // nwg = 512
  const int wg = (id & 7) * 64 + (id >> 3);
  const int b = wg >> 5, rem = wg & 31, by = rem >> 2, bx = rem & 3;
  const int t = threadIdx.x, lane = t & 63, wid = t >> 6;
  const int wrow = wid >> 2, wcol = wid & 3, l15 = lane & 15;
  __shared__ _Float16 smem[65536];           // 128 KB
  const _Float16* Ab = Pm + ((size_t)b * LDIM + by * 256) * MDIM;
  const _Float16* Bb = Vt + ((size_t)b * DDIM + bx * 256) * MDIM;
  f32x4v acc[8][4];
#pragma unroll
  for (int i = 0; i < 8; ++i)
#pragma unroll
    for (int j = 0; j < 4; ++j) acc[i][j] = (f32x4v){0.f, 0.f, 0.f, 0.f};

  gemm_loop(Ab, Bb, MDIM, MDIM / 64, smem, acc, wid, lane, wrow, wcol);

  // epilogue: 8 panels of 32 rows staged f32 in LDS, float4 nt stores
  float* sC = (float*)smem;                  // [32][260]
  const int r32 = t >> 4, cq = (t & 15) * 4;
  float4 o2v[4];
#pragma unroll
  for (int j = 0; j < 4; ++j)
    o2v[j] = *(const float4*)&o2[b * DDIM + bx * 256 + j * 64 + cq];
  __syncthreads();
#pragma unroll
  for (int p = 0; p < 8; ++p) {
    if (wrow == (p >> 2)) {
#pragma unroll
      for (int i2 = 0; i2 < 2; ++i2) {
        const int mi = (p & 3) * 2 + i2;
#pragma unroll
        for (int n = 0; n < 4; ++n)
#pragma unroll
          for (int r = 0; r < 4; ++r) {
            const int lr = i2 * 16 + (lane >> 4) * 4 + r;
            const int col = wcol * 64 + n * 16 + l15;
            sC[lr * 260 + col] = acc[mi][n][r];
          }
      }
    }
    __syncthreads();
    const size_t grow = (size_t)b * LDIM + by * 256 + p * 32 + r32;
    const float* ibp = &input[grow * DDIM + bx * 256];
    float* ob = &out[grow * (4 * DDIM) + bx * 256];
#pragma unroll
    for (int j = 0; j < 4; ++j) {
      const float4 cj = *(const float4*)&sC[r32 * 260 + j * 64 + cq];
      const float4 ij = *(const float4*)&ibp[j * 64 + cq];
      nts4(ij, ob + j * 64 + cq);
      nts4(cj, ob + DDIM + j * 64 + cq);
      nts4(m4(ij, cj), ob + 2 * DDIM + j * 64 + cq);
      nts4(m4(o2v[j], cj), ob + 3 * DDIM + j * 64 + cq);
    }
    __syncthreads();
  }
}

extern "C" void kernel_launch(void* const* d_in, const int* in_sizes, int n_in,
                              void* d_out, int out_size, void* d_ws, size_t ws_size,
                              hipStream_t stream) {
  (void)in_sizes; (void)n_in; (void)out_size; (void)ws_size;
  const float* input  = (const float*)d_in[0];
  const float* memory = (const float*)d_in[1];
  const int*   mask   = (const int*)d_in[2];
  const float* w_in   = (const float*)d_in[3];
  const float* w_mem  = (const float*)d_in[4];
  const float* scale  = (const float*)d_in[5];
  float* out = (float*)d_out;

  char* p = (char*)d_ws;
  _Float16* Qh = (_Float16*)p; p += (size_t)BDIM * LDIM * DDIM * 2;
  _Float16* Kh = (_Float16*)p; p += (size_t)BDIM * MDIM * DDIM * 2;
  _Float16* Vt = (_Float16*)p; p += (size_t)BDIM * DDIM * MDIM * 2;
  _Float16* Sp = (_Float16*)p; p += (size_t)BDIM * LDIM * MDIM * 2;
  float* idot = (float*)p; p += (size_t)BDIM * LDIM * 4;
  float* mdot = (float*)p; p += (size_t)BDIM * MDIM * 4;
  float* rmax = (float*)p; p += (size_t)BDIM * LDIM * 4;
  float* w2   = (float*)p; p += (size_t)BDIM * LDIM * 4;
  float* o2   = (float*)p; p += (size_t)BDIM * DDIM * 4;

  conv_kernel<<<dim3(BDIM * LDIM / 4), dim3(256), 0, stream>>>(
      input, memory, w_in, w_mem, scale, Qh, Kh, idot, mdot);
  tr_kernel<<<dim3(DDIM / 64, MDIM / 64, BDIM), dim3(256), 0, stream>>>(Kh, Vt);
  gemm1_kernel<<<dim3(BDIM * 8 * 8), dim3(512), 0, stream>>>(
      Qh, Kh, idot, mdot, mask, Sp);
  softmax_rows<<<dim3(BDIM * LDIM / 4), dim3(256), 0, stream>>>(Sp, rmax);
  w2a_kernel<<<dim3(BDIM), dim3(256), 0, stream>>>(rmax, w2, o2);
  o2_kernel<<<dim3(LDIM / 128, BDIM), dim3(256), 0, stream>>>(input, w2, o2);
  gemm2_kernel<<<dim3(BDIM * 8 * 4), dim3(512), 0, stream>>>(
      Sp, Vt, input, o2, out);
}

// Round 10
// 587.410 us; speedup vs baseline: 1.3832x; 1.3832x over previous
//
#include <hip/hip_runtime.h>
#include <hip/hip_bf16.h>

// BiAttention: B=16, L=M=2048, D=1024.
//  conv -> tr -> gemm1(S=QK^T+dots,mask) -> softmax_rows -> w2a(+o2 zero) -> o2 -> gemm2(fused epilogue)
// R10 = R8 (proven 551us: m97 128^2 2-barrier GEMMs, (256,4), GL16, xor swizzle,
// LDS-staged vectorized epilogues) with ONE change: 32x32x16 MFMA instead of
// 16x16x32 (-17% matrix-pipe cycles, m06/m119; same LDS traffic, same AGPR).
// C/D layout: col=lane&31, row=(reg&3)+8*(reg>>2)+4*(lane>>5)  [m74/m101].
// 8-phase lane abandoned after 3 failed attempts (R3/R4/R9).

#define BDIM 16
#define LDIM 2048
#define MDIM 2048
#define DDIM 1024
#define NEGF (-60000.0f)

typedef float    f32x4v  __attribute__((ext_vector_type(4)));
typedef float    f32x16v __attribute__((ext_vector_type(16)));
typedef _Float16 half8   __attribute__((ext_vector_type(8)));
typedef _Float16 half4   __attribute__((ext_vector_type(4)));

#define GL16(gp, lp)                                                        \
  __builtin_amdgcn_global_load_lds(                                         \
      (const __attribute__((address_space(1))) unsigned int*)(gp),          \
      (__attribute__((address_space(3))) unsigned int*)(lp), 16, 0, 0)

__device__ __forceinline__ float4 m4(const float4 a, const float4 b) {
  return (float4){a.x * b.x, a.y * b.y, a.z * b.z, a.w * b.w};
}
__device__ __forceinline__ void nts4(const float4 v, float* p) {
  f32x4v w = {v.x, v.y, v.z, v.w};
  __builtin_nontemporal_store(w, (f32x4v*)p);
}

// ---------------- conversion + row dots ----------------
__global__ __launch_bounds__(256) void conv_kernel(
    const float* __restrict__ input, const float* __restrict__ memory,
    const float* __restrict__ w_in, const float* __restrict__ w_mem,
    const float* __restrict__ scale,
    _Float16* __restrict__ Qh, _Float16* __restrict__ Kh,
    float* __restrict__ idot, float* __restrict__ mdot) {
  const int t = threadIdx.x, lane = t & 63, wid = t >> 6;
  const size_t row = (size_t)blockIdx.x * 4 + wid;
  const float* ir  = input  + row * DDIM;
  const float* mrp = memory + row * DDIM;
  float di = 0.f, dm = 0.f;
#pragma unroll
  for (int c = 0; c < 4; ++c) {
    const int off = c * 256 + lane * 4;
    float4 sc4 = *(const float4*)&scale[off];
    float4 wi4 = *(const float4*)&w_in[off];
    float4 wm4 = *(const float4*)&w_mem[off];
    float4 v = *(const float4*)&ir[off];
    di += v.x * wi4.x + v.y * wi4.y + v.z * wi4.z + v.w * wi4.w;
    half4 q = { (_Float16)(v.x * sc4.x), (_Float16)(v.y * sc4.y),
                (_Float16)(v.z * sc4.z), (_Float16)(v.w * sc4.w) };
    *(half4*)&Qh[row * DDIM + off] = q;
    float4 u = *(const float4*)&mrp[off];
    dm += u.x * wm4.x + u.y * wm4.y + u.z * wm4.z + u.w * wm4.w;
    half4 k = { (_Float16)u.x, (_Float16)u.y, (_Float16)u.z, (_Float16)u.w };
    *(half4*)&Kh[row * DDIM + off] = k;
  }
#pragma unroll
  for (int o = 1; o < 64; o <<= 1) {
    di += __shfl_xor(di, o, 64);
    dm += __shfl_xor(dm, o, 64);
  }
  if (lane == 0) { idot[row] = di; mdot[row] = dm; }
}

// ---------------- transpose memory (f16) -> Vt[b][d][m] ----------------
__global__ __launch_bounds__(256) void tr_kernel(const _Float16* __restrict__ Kh,
                                                 _Float16* __restrict__ Vt) {
  const int b = blockIdx.z;
  const int d0 = blockIdx.x * 64, m0 = blockIdx.y * 64;
  __shared__ _Float16 sT[64][80];
  const int t = threadIdx.x;
  {
    const int mr = t >> 2, ch = (t & 3) * 16;
    const _Float16* src = Kh + ((size_t)b * MDIM + m0 + mr) * DDIM + d0 + ch;
    *(half8*)&sT[mr][ch]     = *(const half8*)&src[0];
    *(half8*)&sT[mr][ch + 8] = *(const half8*)&src[8];
  }
  __syncthreads();
  {
    const int dr = t >> 2, mc = (t & 3) * 16;
    union { _Float16 h[16]; half8 v[2]; } tmp;
#pragma unroll
    for (int j = 0; j < 16; ++j) tmp.h[j] = sT[mc + j][dr];
    _Float16* dst = Vt + ((size_t)b * DDIM + d0 + dr) * MDIM + m0 + mc;
    *(half8*)&dst[0] = tmp.v[0];
    *(half8*)&dst[8] = tmp.v[1];
  }
}

// ============ m97-style 128^2 GEMM core, 32x32x16 MFMA ============
__device__ __forceinline__ void stage128(const _Float16* __restrict__ Ab,
                                         const _Float16* __restrict__ Bb,
                                         _Float16* sAb, _Float16* sBb,
                                         int stride, int k0, int wid, int lane) {
  const int rsub = lane >> 3;
  const int sc = ((lane & 7) ^ rsub) * 8;
#pragma unroll
  for (int j = 0; j < 4; ++j) {
    const int r0 = wid * 32 + j * 8;
    const size_t go = (size_t)(r0 + rsub) * stride + k0 + sc;
    GL16(Ab + go, sAb + r0 * 64);
    GL16(Bb + go, sBb + r0 * 64);
  }
}

// one K=64 step: 16 swizzled ds_read_b128 + 16 x mfma_32x32x16
__device__ __forceinline__ void compute128(const _Float16* sAb, const _Float16* sBb,
                                           f32x16v acc[2][2], int wr, int wc,
                                           int lane) {
  const int l31 = lane & 31, hi = lane >> 5;
#pragma unroll
  for (int ks = 0; ks < 4; ++ks) {
    const int chunk = ks * 2 + hi;           // k-chunk of 8 halfs (0..7)
    half8 aF[2], bF[2];
#pragma unroll
    for (int i = 0; i < 2; ++i) {
      const int ra = wr * 64 + i * 32 + l31;
      aF[i] = *(const half8*)&sAb[ra * 64 + ((chunk ^ (ra & 7)) << 3)];
      const int rb = wc * 64 + i * 32 + l31;
      bF[i] = *(const half8*)&sBb[rb * 64 + ((chunk ^ (rb & 7)) << 3)];
    }
#pragma unroll
    for (int mi = 0; mi < 2; ++mi)
#pragma unroll
      for (int ni = 0; ni < 2; ++ni)
        acc[mi][ni] = __builtin_amdgcn_mfma_f32_32x32x16_f16(aF[mi], bF[ni],
                                                             acc[mi][ni], 0, 0, 0);
  }
}

// ---------------- GEMM1: S = Q @ K^T + dots, masked ----------------
__global__ __launch_bounds__(256, 4) void gemm1_kernel(
    const _Float16* __restrict__ Qh, const _Float16* __restrict__ Kh,
    const float* __restrict__ idot, const float* __restrict__ mdot,
    const int* __restrict__ mask, _Float16* __restrict__ Sp) {
  const int id = blockIdx.x;                  // nwg = 4096
  const int wg = (id & 7) * 512 + (id >> 3);
  const int b = wg >> 8, rem = wg & 255, by = rem >> 4, bx = rem & 15;
  const int t = threadIdx.x, lane = t & 63, wid = t >> 6;
  const int wr = wid >> 1, wc = wid & 1;
  __shared__ union SM1 {
    struct { _Float16 a[128 * 64]; _Float16 b[128 * 64]; } ab;
    _Float16 s[128 * 140];                     // padded S-tile stage
  } sm;
  __shared__ float s_dl[128], s_dm[128];
  __shared__ int   s_ml[128], s_mm[128];
  if (t < 128) {
    s_dl[t] = idot[b * LDIM + by * 128 + t];
    s_ml[t] = mask[b * LDIM + by * 128 + t];
    s_dm[t] = mdot[b * MDIM + bx * 128 + t];
    s_mm[t] = mask[b * MDIM + bx * 128 + t];
  }
  const _Float16* Ab = Qh + ((size_t)b * LDIM + by * 128) * DDIM;
  const _Float16* Bb = Kh + ((size_t)b * MDIM + bx * 128) * DDIM;
  f32x16v acc[2][2];
#pragma unroll
  for (int i = 0; i < 2; ++i)
#pragma unroll
    for (int j = 0; j < 2; ++j)
#pragma unroll
      for (int k = 0; k < 16; ++k) acc[i][j][k] = 0.f;

  for (int ks = 0; ks < DDIM / 64; ++ks) {
    __syncthreads();
    stage128(Ab, Bb, sm.ab.a, sm.ab.b, DDIM, ks * 64, wid, lane);
    __syncthreads();
    compute128(sm.ab.a, sm.ab.b, acc, wr, wc, lane);
  }

  // epilogue: stage f16 S-tile in LDS (32x32 C/D mapping), then half8 writes
  __syncthreads();
  const int l31 = lane & 31, hi = lane >> 5;
#pragma unroll
  for (int mi = 0; mi < 2; ++mi)
#pragma unroll
    for (int ni = 0; ni < 2; ++ni)
#pragma unroll
      for (int rg = 0; rg < 16; ++rg) {
        const int lrow = wr * 64 + mi * 32 + (rg & 3) + 8 * (rg >> 2) + 4 * hi;
        const int lcol = wc * 64 + ni * 32 + l31;
        float s = acc[mi][ni][rg] + s_dl[lrow] + s_dm[lcol];
        if ((s_ml[lrow] | s_mm[lcol]) != 0) s = NEGF;
        sm.s[lrow * 140 + lcol] = (_Float16)s;
      }
  __syncthreads();
  const int r16 = t >> 4, c8 = (t & 15) * 8;
#pragma unroll
  for (int rd = 0; rd < 8; ++rd) {
    const int lrow = rd * 16 + r16;
    half8 v = *(const half8*)&sm.s[lrow * 140 + c8];
    *(half8*)&Sp[((size_t)b * LDIM + by * 128 + lrow) * MDIM + bx * 128 + c8] = v;
  }
}

// ---------------- per-row softmax (in place) + rowmax ----------------
__global__ __launch_bounds__(256) void softmax_rows(_Float16* __restrict__ Sp,
                                                    float* __restrict__ rmax) {
  const int t = threadIdx.x, lane = t & 63, wid = t >> 6;
  const size_t row = (size_t)blockIdx.x * 4 + wid;
  _Float16* rp = Sp + row * (size_t)MDIM;
  float s[32];
#pragma unroll
  for (int c = 0; c < 4; ++c) {
    half8 v = *(const half8*)&rp[c * 512 + lane * 8];
#pragma unroll
    for (int j = 0; j < 8; ++j) s[c * 8 + j] = (float)v[j];
  }
  float m = -3.0e38f;
#pragma unroll
  for (int i = 0; i < 32; ++i) m = fmaxf(m, s[i]);
#pragma unroll
  for (int o = 1; o < 64; o <<= 1) m = fmaxf(m, __shfl_xor(m, o, 64));
  float sum = 0.f;
#pragma unroll
  for (int i = 0; i < 32; ++i) { s[i] = __expf(s[i] - m); sum += s[i]; }
#pragma unroll
  for (int o = 1; o < 64; o <<= 1) sum += __shfl_xor(sum, o, 64);
  const float inv = 1.f / sum;
#pragma unroll
  for (int c = 0; c < 4; ++c) {
    half8 v;
#pragma unroll
    for (int j = 0; j < 8; ++j) v[j] = (_Float16)(s[c * 8 + j] * inv);
    *(half8*)&rp[c * 512 + lane * 8] = v;
  }
  if (lane == 0) rmax[row] = m;
}

// ---------------- w2 = softmax_l(rowmax) per batch (+ zero o2) ----------------
__global__ __launch_bounds__(256) void w2a_kernel(const float* __restrict__ rmax,
                                                  float* __restrict__ w2,
                                                  float* __restrict__ o2) {
  const int b = blockIdx.x, t = threadIdx.x;
  ((float4*)(o2 + (size_t)b * DDIM))[t] = (float4){0.f, 0.f, 0.f, 0.f};
  __shared__ float red[256];
  const float* rm = rmax + (size_t)b * LDIM;
  float vals[8]; float lm = -3.0e38f;
#pragma unroll
  for (int j = 0; j < 8; ++j) { vals[j] = rm[t + j * 256]; lm = fmaxf(lm, vals[j]); }
  red[t] = lm; __syncthreads();
  for (int s = 128; s > 0; s >>= 1) {
    if (t < s) red[t] = fmaxf(red[t], red[t + s]);
    __syncthreads();
  }
  const float M = red[0]; __syncthreads();
  float ls = 0.f;
#pragma unroll
  for (int j = 0; j < 8; ++j) ls += __expf(vals[j] - M);
  red[t] = ls; __syncthreads();
  for (int s = 128; s > 0; s >>= 1) {
    if (t < s) red[t] += red[t + s];
    __syncthreads();
  }
  const float inv = 1.f / red[0];
#pragma unroll
  for (int j = 0; j < 8; ++j) w2[(size_t)b * LDIM + t + j * 256] = __expf(vals[j] - M) * inv;
}

// ---------------- o2 ----------------
__global__ __launch_bounds__(256) void o2_kernel(const float* __restrict__ input,
                                                 const float* __restrict__ w2,
                                                 float* __restrict__ o2) {
  const int b = blockIdx.y, ch = blockIdx.x, t = threadIdx.x;
  __shared__ float sw[128];
  if (t < 128) sw[t] = w2[(size_t)b * LDIM + ch * 128 + t];
  __syncthreads();
  const float* ib = input + ((size_t)b * LDIM + ch * 128) * DDIM;
  float4 acc = {0.f, 0.f, 0.f, 0.f};
  for (int l = 0; l < 128; ++l) {
    const float w = sw[l];
    float4 v = *(const float4*)&ib[(size_t)l * DDIM + t * 4];
    acc.x += w * v.x; acc.y += w * v.y; acc.z += w * v.z; acc.w += w * v.w;
  }
  atomicAdd(&o2[b * DDIM + t * 4 + 0], acc.x);
  atomicAdd(&o2[b * DDIM + t * 4 + 1], acc.y);
  atomicAdd(&o2[b * DDIM + t * 4 + 2], acc.z);
  atomicAdd(&o2[b * DDIM + t * 4 + 3], acc.w);
}

// ---------------- GEMM2: o1 = P @ V, fused vectorized epilogue ----------------
__global__ __launch_bounds__(256, 4) void gemm2_kernel(
    const _Float16* __restrict__ Pm, const _Float16* __restrict__ Vt,
    const float* __restrict__ input, const float* __restrict__ o2,
    float* __restrict__ out) {
  const int id = blockIdx.x;                  // nwg = 2048
  const int wg = (id & 7) * 256 + (id >> 3);
  const int b = wg >> 7, rem = wg & 127, by = rem >> 3, bx = rem & 7;
  const int t = threadIdx.x, lane = t & 63, wid = t >> 6;
  const int wr = wid >> 1, wc = wid & 1;
  __shared__ union SM2 {
    struct { _Float16 a[128 * 64]; _Float16 b[128 * 64]; } ab;
    float c[16 * 132];                        // padded C-panel stage
  } sm;
  const _Float16* Ab = Pm + ((size_t)b * LDIM + by * 128) * MDIM;
  const _Float16* Bb = Vt + ((size_t)b * DDIM + bx * 128) * MDIM;
  f32x16v acc[2][2];
#pragma unroll
  for (int i = 0; i < 2; ++i)
#pragma unroll
    for (int j = 0; j < 2; ++j)
#pragma unroll
      for (int k = 0; k < 16; ++k) acc[i][j][k] = 0.f;

  for (int ks = 0; ks < MDIM / 64; ++ks) {
    __syncthreads();
    stage128(Ab, Bb, sm.ab.a, sm.ab.b, MDIM, ks * 64, wid, lane);
    __syncthreads();
    compute128(sm.ab.a, sm.ab.b, acc, wr, wc, lane);
  }

  // epilogue: 8 panels of 16 rows x 128 cols, staged f32 in LDS, float4 nt out
  // panel pp -> wave wr==pp>>2, mi=(pp>>1)&1, regs (pp&1)*8..+7
  const int cq = (t & 15) * 4;
  const float4 o2a = *(const float4*)&o2[b * DDIM + bx * 128 + cq];
  const float4 o2b = *(const float4*)&o2[b * DDIM + bx * 128 + 64 + cq];
  const int r16 = t >> 4;
  const int l31 = lane & 31, hi = lane >> 5;
  __syncthreads();
#pragma unroll
  for (int pp = 0; pp < 8; ++pp) {
    if (wr == (pp >> 2)) {
      const int mi = (pp >> 1) & 1;
      const int rh = pp & 1;
#pragma unroll
      for (int ni = 0; ni < 2; ++ni)
#pragma unroll
        for (int q = 0; q < 8; ++q) {
          const int rg = rh * 8 + q;
          const int lr = (q & 3) + 8 * (q >> 2) + 4 * hi;   // 0..15
          sm.c[lr * 132 + wc * 64 + ni * 32 + l31] = acc[mi][ni][rg];
        }
    }
    __syncthreads();
    const size_t l = (size_t)by * 128 + pp * 16 + r16;
    const float4 c0 = *(const float4*)&sm.c[r16 * 132 + cq];
    const float4 c1 = *(const float4*)&sm.c[r16 * 132 + 64 + cq];
    const float* ibp = &input[((size_t)b * LDIM + l) * DDIM + bx * 128];
    const float4 i0 = *(const float4*)&ibp[cq];
    const float4 i1 = *(const float4*)&ibp[64 + cq];
    float* ob = &out[((size_t)b * LDIM + l) * (4 * DDIM) + bx * 128];
    nts4(i0, ob + cq);
    nts4(i1, ob + 64 + cq);
    nts4(c0, ob + DDIM + cq);
    nts4(c1, ob + DDIM + 64 + cq);
    nts4(m4(i0, c0), ob + 2 * DDIM + cq);
    nts4(m4(i1, c1), ob + 2 * DDIM + 64 + cq);
    nts4(m4(o2a, c0), ob + 3 * DDIM + cq);
    nts4(m4(o2b, c1), ob + 3 * DDIM + 64 + cq);
    __syncthreads();
  }
}

extern "C" void kernel_launch(void* const* d_in, const int* in_sizes, int n_in,
                              void* d_out, int out_size, void* d_ws, size_t ws_size,
                              hipStream_t stream) {
  (void)in_sizes; (void)n_in; (void)out_size; (void)ws_size;
  const float* input  = (const float*)d_in[0];
  const float* memory = (const float*)d_in[1];
  const int*   mask   = (const int*)d_in[2];
  const float* w_in   = (const float*)d_in[3];
  const float* w_mem  = (const float*)d_in[4];
  const float* scale  = (const float*)d_in[5];
  float* out = (float*)d_out;

  char* p = (char*)d_ws;
  _Float16* Qh = (_Float16*)p; p += (size_t)BDIM * LDIM * DDIM * 2;
  _Float16* Kh = (_Float16*)p; p += (size_t)BDIM * MDIM * DDIM * 2;
  _Float16* Vt = (_Float16*)p; p += (size_t)BDIM * DDIM * MDIM * 2;
  _Float16* Sp = (_Float16*)p; p += (size_t)BDIM * LDIM * MDIM * 2;
  float* idot = (float*)p; p += (size_t)BDIM * LDIM * 4;
  float* mdot = (float*)p; p += (size_t)BDIM * MDIM * 4;
  float* rmax = (float*)p; p += (size_t)BDIM * LDIM * 4;
  float* w2   = (float*)p; p += (size_t)BDIM * LDIM * 4;
  float* o2   = (float*)p; p += (size_t)BDIM * DDIM * 4;

  conv_kernel<<<dim3(BDIM * LDIM / 4), dim3(256), 0, stream>>>(
      input, memory, w_in, w_mem, scale, Qh, Kh, idot, mdot);
  tr_kernel<<<dim3(DDIM / 64, MDIM / 64, BDIM), dim3(256), 0, stream>>>(Kh, Vt);
  gemm1_kernel<<<dim3(BDIM * 16 * 16), dim3(256), 0, stream>>>(
      Qh, Kh, idot, mdot, mask, Sp);
  softmax_rows<<<dim3(BDIM * LDIM / 4), dim3(256), 0, stream>>>(Sp, rmax);
  w2a_kernel<<<dim3(BDIM), dim3(256), 0, stream>>>(rmax, w2, o2);
  o2_kernel<<<dim3(LDIM / 128, BDIM), dim3(256), 0, stream>>>(input, w2, o2);
  gemm2_kernel<<<dim3(BDIM * 16 * 8), dim3(256), 0, stream>>>(
      Sp, Vt, input, o2, out);
}

// Round 11
// 558.082 us; speedup vs baseline: 1.4559x; 1.0526x over previous
//
#include <hip/hip_runtime.h>
#include <hip/hip_bf16.h>

// BiAttention: B=16, L=M=2048, D=1024.
//  conv -> tr -> gemm1(S=QK^T+dots,mask) -> softmax_rows -> w2a(+o2 zero) -> o2 -> gemm2(fused epilogue)
// R11 = R8 (proven 551us: m97 128^2 2-barrier GEMMs, 16x16x32 MFMA, (256,4),
// GL16, xor swizzle, LDS-staged vectorized epilogues) + traffic cut:
//  conv also writes inH = f16(input); o2 and gemm2-epilogue read inH instead
//  of f32 input (-512 MB HBM reads, +64 MB write). out[0]=f32(f16(input)):
//  rounding ~3e-3 absolute, threshold 0.108.
// Closed lanes: 8-phase (R3/R4/R9 all lost to m97 structure), 32x32 MFMA
// (R10: swizzle period 8 < 32-row fragment group -> 4-way LDS conflict).

#define BDIM 16
#define LDIM 2048
#define MDIM 2048
#define DDIM 1024
#define NEGF (-60000.0f)

typedef float    f32x4v __attribute__((ext_vector_type(4)));
typedef _Float16 half8  __attribute__((ext_vector_type(8)));
typedef _Float16 half4  __attribute__((ext_vector_type(4)));

#define GL16(gp, lp)                                                        \
  __builtin_amdgcn_global_load_lds(                                         \
      (const __attribute__((address_space(1))) unsigned int*)(gp),          \
      (__attribute__((address_space(3))) unsigned int*)(lp), 16, 0, 0)

__device__ __forceinline__ float4 m4(const float4 a, const float4 b) {
  return (float4){a.x * b.x, a.y * b.y, a.z * b.z, a.w * b.w};
}
__device__ __forceinline__ void nts4(const float4 v, float* p) {
  f32x4v w = {v.x, v.y, v.z, v.w};
  __builtin_nontemporal_store(w, (f32x4v*)p);
}
__device__ __forceinline__ float4 h2f4(const half4 h) {
  return (float4){(float)h[0], (float)h[1], (float)h[2], (float)h[3]};
}

// ---------------- conversion + row dots (+ inH shadow copy) ----------------
__global__ __launch_bounds__(256) void conv_kernel(
    const float* __restrict__ input, const float* __restrict__ memory,
    const float* __restrict__ w_in, const float* __restrict__ w_mem,
    const float* __restrict__ scale,
    _Float16* __restrict__ Qh, _Float16* __restrict__ Kh,
    _Float16* __restrict__ inH,
    float* __restrict__ idot, float* __restrict__ mdot) {
  const int t = threadIdx.x, lane = t & 63, wid = t >> 6;
  const size_t row = (size_t)blockIdx.x * 4 + wid;
  const float* ir  = input  + row * DDIM;
  const float* mrp = memory + row * DDIM;
  float di = 0.f, dm = 0.f;
#pragma unroll
  for (int c = 0; c < 4; ++c) {
    const int off = c * 256 + lane * 4;
    float4 sc4 = *(const float4*)&scale[off];
    float4 wi4 = *(const float4*)&w_in[off];
    float4 wm4 = *(const float4*)&w_mem[off];
    float4 v = *(const float4*)&ir[off];
    di += v.x * wi4.x + v.y * wi4.y + v.z * wi4.z + v.w * wi4.w;
    half4 q = { (_Float16)(v.x * sc4.x), (_Float16)(v.y * sc4.y),
                (_Float16)(v.z * sc4.z), (_Float16)(v.w * sc4.w) };
    *(half4*)&Qh[row * DDIM + off] = q;
    half4 hin = { (_Float16)v.x, (_Float16)v.y, (_Float16)v.z, (_Float16)v.w };
    *(half4*)&inH[row * DDIM + off] = hin;
    float4 u = *(const float4*)&mrp[off];
    dm += u.x * wm4.x + u.y * wm4.y + u.z * wm4.z + u.w * wm4.w;
    half4 k = { (_Float16)u.x, (_Float16)u.y, (_Float16)u.z, (_Float16)u.w };
    *(half4*)&Kh[row * DDIM + off] = k;
  }
#pragma unroll
  for (int o = 1; o < 64; o <<= 1) {
    di += __shfl_xor(di, o, 64);
    dm += __shfl_xor(dm, o, 64);
  }
  if (lane == 0) { idot[row] = di; mdot[row] = dm; }
}

// ---------------- transpose memory (f16) -> Vt[b][d][m] ----------------
__global__ __launch_bounds__(256) void tr_kernel(const _Float16* __restrict__ Kh,
                                                 _Float16* __restrict__ Vt) {
  const int b = blockIdx.z;
  const int d0 = blockIdx.x * 64, m0 = blockIdx.y * 64;
  __shared__ _Float16 sT[64][80];
  const int t = threadIdx.x;
  {
    const int mr = t >> 2, ch = (t & 3) * 16;
    const _Float16* src = Kh + ((size_t)b * MDIM + m0 + mr) * DDIM + d0 + ch;
    *(half8*)&sT[mr][ch]     = *(const half8*)&src[0];
    *(half8*)&sT[mr][ch + 8] = *(const half8*)&src[8];
  }
  __syncthreads();
  {
    const int dr = t >> 2, mc = (t & 3) * 16;
    union { _Float16 h[16]; half8 v[2]; } tmp;
#pragma unroll
    for (int j = 0; j < 16; ++j) tmp.h[j] = sT[mc + j][dr];
    _Float16* dst = Vt + ((size_t)b * DDIM + d0 + dr) * MDIM + m0 + mc;
    *(half8*)&dst[0] = tmp.v[0];
    *(half8*)&dst[8] = tmp.v[1];
  }
}

// ============ m97-style 128^2 GEMM core (R5/R8, proven) ============
__device__ __forceinline__ void stage128(const _Float16* __restrict__ Ab,
                                         const _Float16* __restrict__ Bb,
                                         _Float16* sAb, _Float16* sBb,
                                         int stride, int k0, int wid, int lane) {
  const int rsub = lane >> 3;
  const int sc = ((lane & 7) ^ rsub) * 8;
#pragma unroll
  for (int j = 0; j < 4; ++j) {
    const int r0 = wid * 32 + j * 8;
    const size_t go = (size_t)(r0 + rsub) * stride + k0 + sc;
    GL16(Ab + go, sAb + r0 * 64);
    GL16(Bb + go, sBb + r0 * 64);
  }
}

__device__ __forceinline__ void compute128(const _Float16* sAb, const _Float16* sBb,
                                           f32x4v acc[4][4], int wr, int wc,
                                           int lane) {
  const int l15 = lane & 15;
#pragma unroll
  for (int kk = 0; kk < 2; ++kk) {
    const int colh = ((kk * 4 + (lane >> 4)) ^ (lane & 7)) * 8;
    half8 aF[4], bF[4];
#pragma unroll
    for (int i = 0; i < 4; ++i) {
      aF[i] = *(const half8*)&sAb[(wr * 64 + i * 16 + l15) * 64 + colh];
      bF[i] = *(const half8*)&sBb[(wc * 64 + i * 16 + l15) * 64 + colh];
    }
#pragma unroll
    for (int mi = 0; mi < 4; ++mi)
#pragma unroll
      for (int ni = 0; ni < 4; ++ni)
        acc[mi][ni] = __builtin_amdgcn_mfma_f32_16x16x32_f16(aF[mi], bF[ni],
                                                             acc[mi][ni], 0, 0, 0);
  }
}

// ---------------- GEMM1: S = Q @ K^T + dots, masked ----------------
__global__ __launch_bounds__(256, 4) void gemm1_kernel(
    const _Float16* __restrict__ Qh, const _Float16* __restrict__ Kh,
    const float* __restrict__ idot, const float* __restrict__ mdot,
    const int* __restrict__ mask, _Float16* __restrict__ Sp) {
  const int id = blockIdx.x;                  // nwg = 4096
  const int wg = (id & 7) * 512 + (id >> 3);
  const int b = wg >> 8, rem = wg & 255, by = rem >> 4, bx = rem & 15;
  const int t = threadIdx.x, lane = t & 63, wid = t >> 6;
  const int wr = wid >> 1, wc = wid & 1;
  __shared__ union SM1 {
    struct { _Float16 a[128 * 64]; _Float16 b[128 * 64]; } ab;
    _Float16 s[128 * 140];                     // padded S-tile stage
  } sm;
  __shared__ float s_dl[128], s_dm[128];
  __shared__ int   s_ml[128], s_mm[128];
  if (t < 128) {
    s_dl[t] = idot[b * LDIM + by * 128 + t];
    s_ml[t] = mask[b * LDIM + by * 128 + t];
    s_dm[t] = mdot[b * MDIM + bx * 128 + t];
    s_mm[t] = mask[b * MDIM + bx * 128 + t];
  }
  const _Float16* Ab = Qh + ((size_t)b * LDIM + by * 128) * DDIM;
  const _Float16* Bb = Kh + ((size_t)b * MDIM + bx * 128) * DDIM;
  f32x4v acc[4][4];
#pragma unroll
  for (int i = 0; i < 4; ++i)
#pragma unroll
    for (int j = 0; j < 4; ++j) acc[i][j] = (f32x4v){0.f, 0.f, 0.f, 0.f};

  for (int ks = 0; ks < DDIM / 64; ++ks) {
    __syncthreads();
    stage128(Ab, Bb, sm.ab.a, sm.ab.b, DDIM, ks * 64, wid, lane);
    __syncthreads();
    compute128(sm.ab.a, sm.ab.b, acc, wr, wc, lane);
  }

  // epilogue: stage f16 S-tile in LDS, then half8 row writes
  __syncthreads();
  const int rb = wr * 64, cb = wc * 64;
#pragma unroll
  for (int mi = 0; mi < 4; ++mi)
#pragma unroll
    for (int ni = 0; ni < 4; ++ni)
#pragma unroll
      for (int r = 0; r < 4; ++r) {
        const int lrow = rb + mi * 16 + (lane >> 4) * 4 + r;
        const int lcol = cb + ni * 16 + (lane & 15);
        float s = acc[mi][ni][r] + s_dl[lrow] + s_dm[lcol];
        if ((s_ml[lrow] | s_mm[lcol]) != 0) s = NEGF;
        sm.s[lrow * 140 + lcol] = (_Float16)s;
      }
  __syncthreads();
  const int r16 = t >> 4, c8 = (t & 15) * 8;
#pragma unroll
  for (int rd = 0; rd < 8; ++rd) {
    const int lrow = rd * 16 + r16;
    half8 v = *(const half8*)&sm.s[lrow * 140 + c8];
    *(half8*)&Sp[((size_t)b * LDIM + by * 128 + lrow) * MDIM + bx * 128 + c8] = v;
  }
}

// ---------------- per-row softmax (in place) + rowmax ----------------
__global__ __launch_bounds__(256) void softmax_rows(_Float16* __restrict__ Sp,
                                                    float* __restrict__ rmax) {
  const int t = threadIdx.x, lane = t & 63, wid = t >> 6;
  const size_t row = (size_t)blockIdx.x * 4 + wid;
  _Float16* rp = Sp + row * (size_t)MDIM;
  float s[32];
#pragma unroll
  for (int c = 0; c < 4; ++c) {
    half8 v = *(const half8*)&rp[c * 512 + lane * 8];
#pragma unroll
    for (int j = 0; j < 8; ++j) s[c * 8 + j] = (float)v[j];
  }
  float m = -3.0e38f;
#pragma unroll
  for (int i = 0; i < 32; ++i) m = fmaxf(m, s[i]);
#pragma unroll
  for (int o = 1; o < 64; o <<= 1) m = fmaxf(m, __shfl_xor(m, o, 64));
  float sum = 0.f;
#pragma unroll
  for (int i = 0; i < 32; ++i) { s[i] = __expf(s[i] - m); sum += s[i]; }
#pragma unroll
  for (int o = 1; o < 64; o <<= 1) sum += __shfl_xor(sum, o, 64);
  const float inv = 1.f / sum;
#pragma unroll
  for (int c = 0; c < 4; ++c) {
    half8 v;
#pragma unroll
    for (int j = 0; j < 8; ++j) v[j] = (_Float16)(s[c * 8 + j] * inv);
    *(half8*)&rp[c * 512 + lane * 8] = v;
  }
  if (lane == 0) rmax[row] = m;
}

// ---------------- w2 = softmax_l(rowmax) per batch (+ zero o2) ----------------
__global__ __launch_bounds__(256) void w2a_kernel(const float* __restrict__ rmax,
                                                  float* __restrict__ w2,
                                                  float* __restrict__ o2) {
  const int b = blockIdx.x, t = threadIdx.x;
  ((float4*)(o2 + (size_t)b * DDIM))[t] = (float4){0.f, 0.f, 0.f, 0.f};
  __shared__ float red[256];
  const float* rm = rmax + (size_t)b * LDIM;
  float vals[8]; float lm = -3.0e38f;
#pragma unroll
  for (int j = 0; j < 8; ++j) { vals[j] = rm[t + j * 256]; lm = fmaxf(lm, vals[j]); }
  red[t] = lm; __syncthreads();
  for (int s = 128; s > 0; s >>= 1) {
    if (t < s) red[t] = fmaxf(red[t], red[t + s]);
    __syncthreads();
  }
  const float M = red[0]; __syncthreads();
  float ls = 0.f;
#pragma unroll
  for (int j = 0; j < 8; ++j) ls += __expf(vals[j] - M);
  red[t] = ls; __syncthreads();
  for (int s = 128; s > 0; s >>= 1) {
    if (t < s) red[t] += red[t + s];
    __syncthreads();
  }
  const float inv = 1.f / red[0];
#pragma unroll
  for (int j = 0; j < 8; ++j) w2[(size_t)b * LDIM + t + j * 256] = __expf(vals[j] - M) * inv;
}

// ---------------- o2 (reads f16 shadow) ----------------
__global__ __launch_bounds__(256) void o2_kernel(const _Float16* __restrict__ inH,
                                                 const float* __restrict__ w2,
                                                 float* __restrict__ o2) {
  const int b = blockIdx.y, ch = blockIdx.x, t = threadIdx.x;
  __shared__ float sw[128];
  if (t < 128) sw[t] = w2[(size_t)b * LDIM + ch * 128 + t];
  __syncthreads();
  const _Float16* ib = inH + ((size_t)b * LDIM + ch * 128) * DDIM;
  float4 acc = {0.f, 0.f, 0.f, 0.f};
  for (int l = 0; l < 128; ++l) {
    const float w = sw[l];
    const float4 v = h2f4(*(const half4*)&ib[(size_t)l * DDIM + t * 4]);
    acc.x += w * v.x; acc.y += w * v.y; acc.z += w * v.z; acc.w += w * v.w;
  }
  atomicAdd(&o2[b * DDIM + t * 4 + 0], acc.x);
  atomicAdd(&o2[b * DDIM + t * 4 + 1], acc.y);
  atomicAdd(&o2[b * DDIM + t * 4 + 2], acc.z);
  atomicAdd(&o2[b * DDIM + t * 4 + 3], acc.w);
}

// ---------------- GEMM2: o1 = P @ V, fused vectorized epilogue ----------------
__global__ __launch_bounds__(256, 4) void gemm2_kernel(
    const _Float16* __restrict__ Pm, const _Float16* __restrict__ Vt,
    const _Float16* __restrict__ inH, const float* __restrict__ o2,
    float* __restrict__ out) {
  const int id = blockIdx.x;                  // nwg = 2048
  const int wg = (id & 7) * 256 + (id >> 3);
  const int b = wg >> 7, rem = wg & 127, by = rem >> 3, bx = rem & 7;
  const int t = threadIdx.x, lane = t & 63, wid = t >> 6;
  const int wr = wid >> 1, wc = wid & 1;
  __shared__ union SM2 {
    struct { _Float16 a[128 * 64]; _Float16 b[128 * 64]; } ab;
    float c[16 * 132];                        // padded C-panel stage
  } sm;
  const _Float16* Ab = Pm + ((size_t)b * LDIM + by * 128) * MDIM;
  const _Float16* Bb = Vt + ((size_t)b * DDIM + bx * 128) * MDIM;
  f32x4v acc[4][4];
#pragma unroll
  for (int i = 0; i < 4; ++i)
#pragma unroll
    for (int j = 0; j < 4; ++j) acc[i][j] = (f32x4v){0.f, 0.f, 0.f, 0.f};

  for (int ks = 0; ks < MDIM / 64; ++ks) {
    __syncthreads();
    stage128(Ab, Bb, sm.ab.a, sm.ab.b, MDIM, ks * 64, wid, lane);
    __syncthreads();
    compute128(sm.ab.a, sm.ab.b, acc, wr, wc, lane);
  }

  // epilogue: 8 panels of 16 rows x 128 cols, staged f32 in LDS, float4 nt out
  const int cq = (t & 15) * 4;
  const float4 o2a = *(const float4*)&o2[b * DDIM + bx * 128 + cq];
  const float4 o2b = *(const float4*)&o2[b * DDIM + bx * 128 + 64 + cq];
  const int r16 = t >> 4;
  __syncthreads();
#pragma unroll
  for (int pp = 0; pp < 8; ++pp) {
    if (wr == (pp >> 2)) {
      const int pmi = pp & 3;
#pragma unroll
      for (int ni = 0; ni < 4; ++ni)
#pragma unroll
        for (int r = 0; r < 4; ++r)
          sm.c[((lane >> 4) * 4 + r) * 132 + wc * 64 + ni * 16 + (lane & 15)] =
              acc[pmi][ni][r];
    }
    __syncthreads();
    const size_t l = (size_t)by * 128 + pp * 16 + r16;
    const float4 c0 = *(const float4*)&sm.c[r16 * 132 + cq];
    const float4 c1 = *(const float4*)&sm.c[r16 * 132 + 64 + cq];
    const _Float16* ibp = &inH[((size_t)b * LDIM + l) * DDIM + bx * 128];
    const float4 i0 = h2f4(*(const half4*)&ibp[cq]);
    const float4 i1 = h2f4(*(const half4*)&ibp[64 + cq]);
    float* ob = &out[((size_t)b * LDIM + l) * (4 * DDIM) + bx * 128];
    nts4(i0, ob + cq);
    nts4(i1, ob + 64 + cq);
    nts4(c0, ob + DDIM + cq);
    nts4(c1, ob + DDIM + 64 + cq);
    nts4(m4(i0, c0), ob + 2 * DDIM + cq);
    nts4(m4(i1, c1), ob + 2 * DDIM + 64 + cq);
    nts4(m4(o2a, c0), ob + 3 * DDIM + cq);
    nts4(m4(o2b, c1), ob + 3 * DDIM + 64 + cq);
    __syncthreads();
  }
}

extern "C" void kernel_launch(void* const* d_in, const int* in_sizes, int n_in,
                              void* d_out, int out_size, void* d_ws, size_t ws_size,
                              hipStream_t stream) {
  (void)in_sizes; (void)n_in; (void)out_size; (void)ws_size;
  const float* input  = (const float*)d_in[0];
  const float* memory = (const float*)d_in[1];
  const int*   mask   = (const int*)d_in[2];
  const float* w_in   = (const float*)d_in[3];
  const float* w_mem  = (const float*)d_in[4];
  const float* scale  = (const float*)d_in[5];
  float* out = (float*)d_out;

  char* p = (char*)d_ws;
  _Float16* Qh  = (_Float16*)p; p += (size_t)BDIM * LDIM * DDIM * 2;
  _Float16* Kh  = (_Float16*)p; p += (size_t)BDIM * MDIM * DDIM * 2;
  _Float16* Vt  = (_Float16*)p; p += (size_t)BDIM * DDIM * MDIM * 2;
  _Float16* Sp  = (_Float16*)p; p += (size_t)BDIM * LDIM * MDIM * 2;
  _Float16* inH = (_Float16*)p; p += (size_t)BDIM * LDIM * DDIM * 2;
  float* idot = (float*)p; p += (size_t)BDIM * LDIM * 4;
  float* mdot = (float*)p; p += (size_t)BDIM * MDIM * 4;
  float* rmax = (float*)p; p += (size_t)BDIM * LDIM * 4;
  float* w2   = (float*)p; p += (size_t)BDIM * LDIM * 4;
  float* o2   = (float*)p; p += (size_t)BDIM * DDIM * 4;

  conv_kernel<<<dim3(BDIM * LDIM / 4), dim3(256), 0, stream>>>(
      input, memory, w_in, w_mem, scale, Qh, Kh, inH, idot, mdot);
  tr_kernel<<<dim3(DDIM / 64, MDIM / 64, BDIM), dim3(256), 0, stream>>>(Kh, Vt);
  gemm1_kernel<<<dim3(BDIM * 16 * 16), dim3(256), 0, stream>>>(
      Qh, Kh, idot, mdot, mask, Sp);
  softmax_rows<<<dim3(BDIM * LDIM / 4), dim3(256), 0, stream>>>(Sp, rmax);
  w2a_kernel<<<dim3(BDIM), dim3(256), 0, stream>>>(rmax, w2, o2);
  o2_kernel<<<dim3(LDIM / 128, BDIM), dim3(256), 0, stream>>>(inH, w2, o2);
  gemm2_kernel<<<dim3(BDIM * 16 * 8), dim3(256), 0, stream>>>(
      Sp, Vt, inH, o2, out);
}